// Round 17
// baseline (151.549 us; speedup 1.0000x reference)
//
#include <hip/hip_runtime.h>
#include <stdint.h>

typedef unsigned short u16;
typedef unsigned int u32;
typedef short bf16x8 __attribute__((ext_vector_type(8)));
typedef float f32x4 __attribute__((ext_vector_type(4)));

#define MFMA16(a, b, c) __builtin_amdgcn_mfma_f32_16x16x32_bf16((a), (b), (c), 0, 0, 0)
#define BAR()                              \
  do {                                     \
    __builtin_amdgcn_sched_barrier(0);     \
    __builtin_amdgcn_s_barrier();          \
    __builtin_amdgcn_sched_barrier(0);     \
  } while (0)

__device__ __forceinline__ u16 f2bf(float f) {
  union { float f; u32 u; } v; v.f = f;
  u32 u = v.u;
  u32 r = (u + 0x7FFFu + ((u >> 16) & 1u)) >> 16;  // RNE
  return (u16)r;
}
__device__ __forceinline__ float bf2f(u16 h) {
  union { u32 u; float f; } v; v.u = ((u32)h) << 16;
  return v.f;
}
// packed f32x2 -> bf16x2 (single HW instruction, RNE)
__device__ __forceinline__ u32 cvtpk_bf16(float lo, float hi) {
  u32 r;
  asm("v_cvt_pk_bf16_f32 %0, %1, %2" : "=v"(r) : "v"(lo), "v"(hi));
  return r;
}

// async global->LDS, 16B per lane. LDS base must be wave-uniform (HW adds lane*16).
__device__ __forceinline__ void gload_lds16(const void* g, void* l) {
  __builtin_amdgcn_global_load_lds(
      (const __attribute__((address_space(1))) unsigned int*)g,
      (__attribute__((address_space(3))) unsigned int*)l,
      16, 0, 0);
}

// ---------------- transpose+convert: src f32 [R][C] -> dst bf16 [C][R] ----------------
__global__ __launch_bounds__(256) void transpose_f32_bf16(
    const float* __restrict__ src, u16* __restrict__ dst, int R, int C) {
  __shared__ u16 t[32][33];
  const int bx = blockIdx.x * 32, by = blockIdx.y * 32;
  const int tx = threadIdx.x & 31, ty = threadIdx.x >> 5;  // 32x8
#pragma unroll
  for (int i = 0; i < 32; i += 8)
    t[ty + i][tx] = f2bf(src[(size_t)(by + ty + i) * C + bx + tx]);
  __syncthreads();
#pragma unroll
  for (int i = 0; i < 32; i += 8)
    dst[(size_t)(bx + ty + i) * R + by + tx] = t[tx][ty + i];
}

// ---------------- mask compaction: idx[b][] = unmasked key positions ----------------
__global__ __launch_bounds__(512) void mask_compact(
    const int* __restrict__ mask, int* __restrict__ idx, int* __restrict__ cnt) {
  const int b = blockIdx.x;
  const int tid = threadIdx.x;
  const int lane = tid & 63, wave = tid >> 6;
  __shared__ int wtot[8];
  int m[4], c = 0;
#pragma unroll
  for (int j = 0; j < 4; ++j) {
    m[j] = (mask[b * 2048 + tid * 4 + j] != 0);
    c += m[j];
  }
  int pfx = c;
#pragma unroll
  for (int sh = 1; sh < 64; sh <<= 1) {
    int v = __shfl_up(pfx, sh);
    if (lane >= sh) pfx += v;
  }
  if (lane == 63) wtot[wave] = pfx;
  int epfx = pfx - c;
  __syncthreads();
  int wbase = 0, total = 0;
#pragma unroll
  for (int w = 0; w < 8; ++w) {
    int v = wtot[w];
    if (w < wave) wbase += v;
    total += v;
  }
  int pos = b * 2048 + wbase + epfx;
#pragma unroll
  for (int j = 0; j < 4; ++j)
    if (m[j]) idx[pos++] = tid * 4 + j;
  for (int i = total + tid; i < 2048; i += 512) idx[b * 2048 + i] = 0;
  if (tid == 0) cnt[b] = total;
}

// ------- qkv GEMM, fused f32->bf16 A, DEPTH-2 pipeline (counted vmcnt) -------
// Two A-reg sets + 3-buffer Bs + 2-buffer As. Step T: issue B(T+2)/A(T+2),
// MFMA(T), cvt(T+1) -- its compiler wait is COUNTED (A(T+1) issued a full step
// earlier; the 12 newer T+2 ops stay in flight). In-order vmcnt => B(T+1) landed.
// Loop unrolled x2 so reg-set indices are compile-time (no scratch).
__global__ __launch_bounds__(256) void gemm_a32_bf16(
    const float* __restrict__ A, const u16* __restrict__ Bt,
    const float* __restrict__ bias, u16* __restrict__ Cout,
    int M, int N, int K) {
  __shared__ __align__(16) u16 As[2][128 * 64];
  __shared__ __align__(16) u16 Bs[3][128 * 64];
  const int tid = threadIdx.x;
  const int lane = tid & 63;
  const int wave = tid >> 6;
  const int nwg = gridDim.x;
  const int id = blockIdx.x;
  const int sw = (id & 7) * (nwg >> 3) + (id >> 3);
  const int nx = N >> 7;
  const int m0 = (sw / nx) * 128;
  const int n0 = (sw % nx) * 128;
  const int wm = (wave >> 1) * 64;
  const int wn = (wave & 1) * 64;

  f32x4 acc[4][4] = {};
  const char* Bbase = (const char*)Bt;
  float4 fa0[4], fb0[4], fa1[4], fb1[4];

#define A32_ISSUE_B(ktile, buf)                                                \
  _Pragma("unroll") for (int i = 0; i < 4; ++i) {                              \
    int flat = wave * 1024 + lane * 16 + i * 4096;                             \
    int row = flat >> 7;                                                       \
    int cb = flat & 127;                                                       \
    int scb = cb ^ ((row & 7) << 4);                                           \
    gload_lds16(Bbase + ((size_t)(n0 + row) * K + (ktile)) * 2 + scb,          \
                (char*)&Bs[buf][0] + flat);                                    \
  }

#define A32_LOAD_A(ktile, FA, FB)                                              \
  _Pragma("unroll") for (int i = 0; i < 4; ++i) {                              \
    int flat = wave * 1024 + lane * 16 + i * 4096;                             \
    int row = flat >> 7;                                                       \
    int cb = flat & 127;                                                       \
    const float* ax = A + (size_t)(m0 + row) * K + (ktile) + (cb >> 1);        \
    FA[i] = *(const float4*)ax;                                                \
    FB[i] = *(const float4*)(ax + 4);                                          \
  }

#define A32_CVT(FA, FB, buf)                                                   \
  _Pragma("unroll") for (int i = 0; i < 4; ++i) {                              \
    int flat = wave * 1024 + lane * 16 + i * 4096;                             \
    int row = flat >> 7;                                                       \
    int cb = flat & 127;                                                       \
    union { u32 w[4]; bf16x8 v; } o;                                           \
    o.w[0] = cvtpk_bf16(FA[i].x, FA[i].y);                                     \
    o.w[1] = cvtpk_bf16(FA[i].z, FA[i].w);                                     \
    o.w[2] = cvtpk_bf16(FB[i].x, FB[i].y);                                     \
    o.w[3] = cvtpk_bf16(FB[i].z, FB[i].w);                                     \
    *(bf16x8*)((char*)&As[buf][0] + row * 128 + (cb ^ ((row & 7) << 4))) = o.v; \
  }

  const int nsteps = K >> 6;  // 16

  // prologue: tiles 0 and 1 in flight; cvt(0) waits only for A(0) (counted)
  A32_ISSUE_B(0, 0);
  A32_LOAD_A(0, fa0, fb0);
  A32_ISSUE_B(64, 1);
  A32_LOAD_A(64, fa1, fb1);
  A32_CVT(fa0, fb0, 0);
  asm volatile("s_waitcnt lgkmcnt(0)" ::: "memory");
  BAR();

#define QSTEP(T, FA_L, FB_L, FA_C, FB_C)                                       \
  {                                                                            \
    if ((T) + 2 < nsteps) {                                                    \
      A32_ISSUE_B(((T) + 2) << 6, ((T) + 2) % 3);                              \
      A32_LOAD_A(((T) + 2) << 6, FA_L, FB_L);                                  \
    }                                                                          \
    __builtin_amdgcn_sched_barrier(0);                                         \
    {                                                                          \
      const u16* BsT = &Bs[(T) % 3][0];                                        \
      const u16* AsT = &As[(T) & 1][0];                                        \
      _Pragma("unroll") for (int ks = 0; ks < 2; ++ks) {                       \
        const int col = (lane >> 4) * 8 + ks * 32;                             \
        bf16x8 af[4], bfr[4];                                                  \
        _Pragma("unroll") for (int mt = 0; mt < 4; ++mt) {                     \
          int row = wm + mt * 16 + (lane & 15);                                \
          af[mt] = *(const bf16x8*)((const char*)AsT + row * 128 +             \
                                    ((col * 2) ^ ((row & 7) << 4)));           \
        }                                                                      \
        _Pragma("unroll") for (int nt = 0; nt < 4; ++nt) {                     \
          int row = wn + nt * 16 + (lane & 15);                                \
          bfr[nt] = *(const bf16x8*)((const char*)BsT + row * 128 +            \
                                     ((col * 2) ^ ((row & 7) << 4)));          \
        }                                                                      \
        _Pragma("unroll") for (int mt = 0; mt < 4; ++mt)                       \
          _Pragma("unroll") for (int nt = 0; nt < 4; ++nt)                     \
            acc[mt][nt] = MFMA16(af[mt], bfr[nt], acc[mt][nt]);                \
      }                                                                        \
    }                                                                          \
    __builtin_amdgcn_sched_barrier(0);                                         \
    if ((T) + 1 < nsteps) {                                                    \
      A32_CVT(FA_C, FB_C, ((T) + 1) & 1);                                      \
      asm volatile("s_waitcnt lgkmcnt(0)" ::: "memory");                       \
      BAR();                                                                   \
    }                                                                          \
  }

  for (int tt = 0; tt < nsteps; tt += 2) {
    QSTEP(tt, fa0, fb0, fa1, fb1);      // load A(T+2)->set0 ; cvt A(T+1) from set1
    QSTEP(tt + 1, fa1, fb1, fa0, fb0);  // load ->set1 ; cvt from set0
  }
#undef QSTEP
#undef A32_ISSUE_B
#undef A32_LOAD_A
#undef A32_CVT

  float bv[4];
#pragma unroll
  for (int nt = 0; nt < 4; ++nt)
    bv[nt] = bias[n0 + wn + nt * 16 + (lane & 15)];
#pragma unroll
  for (int mt = 0; mt < 4; ++mt)
#pragma unroll
    for (int nt = 0; nt < 4; ++nt)
#pragma unroll
      for (int r = 0; r < 4; ++r) {
        int m = m0 + wm + mt * 16 + (lane >> 4) * 4 + r;
        int n = n0 + wn + nt * 16 + (lane & 15);
        Cout[(size_t)m * N + n] = f2bf(acc[mt][nt][r] + bv[nt]);
      }
}

// ---------------- GEMM (bf16 A), pipelined dbuf + T2 swizzle ----------------
template <bool OUT_BF16>
__global__ __launch_bounds__(256) void gemm_bf16(
    const u16* __restrict__ A, const u16* __restrict__ Bt,
    const float* __restrict__ bias, void* __restrict__ Cout,
    int M, int N, int K) {
  __shared__ __align__(16) u16 As[2][128 * 64];
  __shared__ __align__(16) u16 Bs[2][128 * 64];
  const int tid = threadIdx.x;
  const int lane = tid & 63;
  const int wave = tid >> 6;
  const int nwg = gridDim.x;
  const int id = blockIdx.x;
  const int sw = (id & 7) * (nwg >> 3) + (id >> 3);
  const int nx = N >> 7;
  const int m0 = (sw / nx) * 128;
  const int n0 = (sw % nx) * 128;
  const int wm = (wave >> 1) * 64;
  const int wn = (wave & 1) * 64;

  f32x4 acc[4][4] = {};

  const char* Abase = (const char*)A;
  const char* Bbase = (const char*)Bt;

#define STAGE_AB(ktile, buf)                                                   \
  _Pragma("unroll") for (int i = 0; i < 4; ++i) {                              \
    int flat = wave * 1024 + lane * 16 + i * 4096;                             \
    int row = flat >> 7;                                                       \
    int cb = flat & 127;                                                       \
    int scb = cb ^ ((row & 7) << 4);                                           \
    gload_lds16(Abase + ((size_t)(m0 + row) * K + (ktile)) * 2 + scb,          \
                (char*)&As[buf][0] + flat);                                    \
    gload_lds16(Bbase + ((size_t)(n0 + row) * K + (ktile)) * 2 + scb,          \
                (char*)&Bs[buf][0] + flat);                                    \
  }

  STAGE_AB(0, 0);

  const int nsteps = K >> 6;
  for (int t = 0; t < nsteps; ++t) {
    asm volatile("s_waitcnt vmcnt(0)" ::: "memory");
    BAR();
    if (t < nsteps - 1) STAGE_AB((t << 6) + 64, (t & 1) ^ 1);
#pragma unroll
    for (int ks = 0; ks < 2; ++ks) {
      const int col = (lane >> 4) * 8 + ks * 32;
      bf16x8 af[4], bfr[4];
#pragma unroll
      for (int mt = 0; mt < 4; ++mt) {
        int row = wm + mt * 16 + (lane & 15);
        af[mt] = *(const bf16x8*)((const char*)&As[t & 1][0] + row * 128 +
                                  ((col * 2) ^ ((row & 7) << 4)));
      }
#pragma unroll
      for (int nt = 0; nt < 4; ++nt) {
        int row = wn + nt * 16 + (lane & 15);
        bfr[nt] = *(const bf16x8*)((const char*)&Bs[t & 1][0] + row * 128 +
                                   ((col * 2) ^ ((row & 7) << 4)));
      }
#pragma unroll
      for (int mt = 0; mt < 4; ++mt)
#pragma unroll
        for (int nt = 0; nt < 4; ++nt)
          acc[mt][nt] = MFMA16(af[mt], bfr[nt], acc[mt][nt]);
    }
  }
#undef STAGE_AB

  float bv[4];
#pragma unroll
  for (int nt = 0; nt < 4; ++nt)
    bv[nt] = bias[n0 + wn + nt * 16 + (lane & 15)];
#pragma unroll
  for (int mt = 0; mt < 4; ++mt)
#pragma unroll
    for (int nt = 0; nt < 4; ++nt)
#pragma unroll
      for (int r = 0; r < 4; ++r) {
        int m = m0 + wm + mt * 16 + (lane >> 4) * 4 + r;
        int n = n0 + wn + nt * 16 + (lane & 15);
        float v = acc[mt][nt][r] + bv[nt];
        if (OUT_BF16)
          ((u16*)Cout)[(size_t)m * N + n] = f2bf(v);
        else
          ((float*)Cout)[(size_t)m * N + n] = v;
      }
}

// ---------------- flash attention (v13: COMPACTED keys via idx gather) ----------
// UNCHANGED from round 16 (~40 us; compaction halves all attention work).
#define T_SEQ 2048
#define ROWQKV 3072
#define SCL 0.180336880f  /* (1/sqrt(64)) * log2(e) */

template <bool SPLIT>
__global__ __launch_bounds__(512) void attn_fwd(
    const u16* __restrict__ qkv, const int* __restrict__ idx,
    const int* __restrict__ cnt, u16* __restrict__ outp,
    float* __restrict__ Ml) {
  __shared__ __align__(16) u16 Ks[2][2][64 * 64];  // [buf][half][storerow][dk], swz s=row&7
  __shared__ __align__(16) u16 Vt[2][2][64 * 64];  // [buf][half][d][cpos], swz row^(row>>3)
  __shared__ __align__(16) u32 lut[256 * 4];       // byte -> 8 x bf16 {0,1}

  const int tid = threadIdx.x;
  const int lane = tid & 63;
  const int wave = tid >> 6;
  const int r15 = lane & 15;
  const int g = lane >> 4;
  const int id = blockIdx.x;
  const int hz = ((id >> 6) << 3) | (id & 7);
  const int qb = (id >> 3) & 7;
  const int h = SPLIT ? (hz >> 2) : (hz >> 1);
  const int z = SPLIT ? (hz & 3) : (hz & 1);
  const int split = SPLIT ? (z >> 1) : 0;
  const int b = SPLIT ? (z & 1) : z;
  const int q0 = qb * 256 + wave * 32;
  const size_t rowb = (size_t)b * T_SEQ;
  const int* idxb = idx + b * 2048;
  const int count = cnt[b];
  const int ntot = (count + 127) >> 7;
  const int nth = (ntot + 1) >> 1;
  const int t0 = (SPLIT && split) ? nth : 0;
  const int nt2 = SPLIT ? (split ? ntot - nth : nth) : ntot;

  for (int i = tid; i < 256; i += 512) {
    union { u32 w[4]; bf16x8 v; } e;
#pragma unroll
    for (int j = 0; j < 4; ++j)
      e.w[j] = (((i >> (2 * j)) & 1) ? 0x3F80u : 0u) |
               (((i >> (2 * j + 1)) & 1) ? 0x3F800000u : 0u);
    *(bf16x8*)((char*)lut + i * 16) = e.v;
  }

  bf16x8 aq[2][2];
#pragma unroll
  for (int mt = 0; mt < 2; ++mt)
#pragma unroll
    for (int ks = 0; ks < 2; ++ks) {
      bf16x8 t = *(const bf16x8*)(qkv +
          (rowb + q0 + mt * 16 + r15) * ROWQKV + h * 64 + g * 8 + ks * 32);
#pragma unroll
      for (int j = 0; j < 8; ++j) t[j] = (short)f2bf(bf2f((u16)t[j]) * SCL);
      aq[mt][ks] = t;
    }

  f32x4 accO[2][4] = {};
  f32x4 ssum[2] = {};
  bf16x8 vr0, vr1;

#define ISSUE_K2(ct, buf)                                                      \
  {                                                                            \
    int L = wave * 1024 + lane * 16;                                           \
    int row = L >> 7;                                                          \
    int cb = L & 127;                                                          \
    int scb = cb ^ ((row & 7) << 4);                                           \
    int prow = ((row >> 4) & 1) * 32 + ((row >> 2) & 3) * 8 +                  \
               (row >> 5) * 4 + (row & 3);                                     \
    int gk0 = idxb[(ct) * 128 + prow];                                         \
    int gk1 = idxb[(ct) * 128 + 64 + prow];                                    \
    gload_lds16((const char*)qkv +                                             \
                    ((rowb + gk0) * ROWQKV + 1024 + h * 64) * 2 + scb,         \
                (char*)&Ks[buf][0][0] + wave * 1024);                          \
    gload_lds16((const char*)qkv +                                             \
                    ((rowb + gk1) * ROWQKV + 1024 + h * 64) * 2 + scb,         \
                (char*)&Ks[buf][1][0] + wave * 1024);                          \
  }

#define LOAD_V2(ct)                                                            \
  {                                                                            \
    int key = tid >> 3;                                                        \
    int gv0 = idxb[(ct) * 128 + key];                                          \
    int gv1 = idxb[(ct) * 128 + 64 + key];                                     \
    vr0 = *(const bf16x8*)(qkv + (rowb + gv0) * ROWQKV + 2048 + h * 64 +       \
                           (tid & 7) * 8);                                     \
    vr1 = *(const bf16x8*)(qkv + (rowb + gv1) * ROWQKV + 2048 + h * 64 +       \
                           (tid & 7) * 8);                                     \
  }

#define WRITE_V2(buf, ct)                                                      \
  {                                                                            \
    int key = tid >> 3;                                                        \
    if ((ct) * 128 + key >= count) {                                           \
      bf16x8 zz = {};                                                          \
      vr0 = zz;                                                                \
    }                                                                          \
    if ((ct) * 128 + 64 + key >= count) {                                      \
      bf16x8 zz = {};                                                          \
      vr1 = zz;                                                                \
    }                                                                          \
    _Pragma("unroll") for (int j = 0; j < 8; ++j) {                            \
      int row = (tid & 7) * 8 + j;                                             \
      int sv = ((row ^ (row >> 3)) & 7) << 4;                                  \
      *(u16*)((char*)&Vt[buf][0][0] + row * 128 + ((key * 2) ^ sv)) =          \
          (u16)vr0[j];                                                         \
      *(u16*)((char*)&Vt[buf][1][0] + row * 128 + ((key * 2) ^ sv)) =          \
          (u16)vr1[j];                                                         \
    }                                                                          \
  }

#define COMPUTE_HALF(H, ct)                                                    \
  {                                                                            \
    f32x4 s[2][4] = {};                                                        \
    _Pragma("unroll") for (int ks = 0; ks < 2; ++ks) {                         \
      bf16x8 bk[4];                                                            \
      _Pragma("unroll") for (int nt = 0; nt < 4; ++nt) {                       \
        int row = nt * 16 + r15;                                               \
        int cb = (g * 8 + ks * 32) * 2;                                        \
        bk[nt] = *(const bf16x8*)((const char*)&Ks[cur][H][0] + row * 128 +    \
                                  (cb ^ ((row & 7) << 4)));                    \
      }                                                                        \
      _Pragma("unroll") for (int mt = 0; mt < 2; ++mt)                         \
        _Pragma("unroll") for (int nt = 0; nt < 4; ++nt)                       \
          s[mt][nt] = MFMA16(bk[nt], aq[mt][ks], s[mt][nt]);                   \
    }                                                                          \
    u32 pk[2][4][2];                                                           \
    _Pragma("unroll") for (int mt = 0; mt < 2; ++mt)                           \
      _Pragma("unroll") for (int nt = 0; nt < 4; ++nt) {                       \
        float e0 = exp2f(s[mt][nt][0]);                                        \
        float e1 = exp2f(s[mt][nt][1]);                                        \
        float e2 = exp2f(s[mt][nt][2]);                                        \
        float e3 = exp2f(s[mt][nt][3]);                                        \
        pk[mt][nt][0] = cvtpk_bf16(e0, e1);                                    \
        pk[mt][nt][1] = cvtpk_bf16(e2, e3);                                    \
      }                                                                        \
    __builtin_amdgcn_s_setprio(1);                                             \
    _Pragma("unroll") for (int ks = 0; ks < 2; ++ks) {                         \
      const int col = g * 8 + ks * 32;                                         \
      bf16x8 bv[4];                                                            \
      _Pragma("unroll") for (int nt = 0; nt < 4; ++nt) {                       \
        int row = nt * 16 + r15;                                               \
        int sv = ((row ^ (row >> 3)) & 7) << 4;                                \
        bv[nt] = *(const bf16x8*)((const char*)&Vt[cur][H][0] + row * 128 +    \
                                  ((col * 2) ^ sv));                           \
      }                                                                        \
      int rbase = count - ((ct) * 128 + (H) * 64 + ks * 32 + g * 8);           \
      int rr = rbase < 0 ? 0 : (rbase > 8 ? 8 : rbase);                        \
      u32 lb = (1u << rr) - 1u;                                                \
      bf16x8 mf = *(const bf16x8*)((const char*)lut + lb * 16);                \
      _Pragma("unroll") for (int mt = 0; mt < 2; ++mt) {                       \
        union { u32 w[4]; bf16x8 v; } ap;                                      \
        ap.w[0] = pk[mt][ks][0];                                               \
        ap.w[1] = pk[mt][ks][1];                                               \
        ap.w[2] = pk[mt][2 + ks][0];                                           \
        ap.w[3] = pk[mt][2 + ks][1];                                           \
        _Pragma("unroll") for (int nt = 0; nt < 4; ++nt)                       \
          accO[mt][nt] = MFMA16(ap.v, bv[nt], accO[mt][nt]);                   \
        ssum[mt] = MFMA16(ap.v, mf, ssum[mt]);                                 \
      }                                                                        \
    }                                                                          \
    __builtin_amdgcn_s_setprio(0);                                             \
  }

  if (nt2 > 0) {
    ISSUE_K2(t0, 0);
    LOAD_V2(t0);
    __syncthreads();
    WRITE_V2(0, t0);
    asm volatile("s_waitcnt lgkmcnt(0)" ::: "memory");
    BAR();

    int cur = 0;
    for (int t = 0; t < nt2; ++t) {
      const int ct = t0 + t;
      if (t < nt2 - 1) {
        ISSUE_K2(ct + 1, cur ^ 1);
        LOAD_V2(ct + 1);
      }

      COMPUTE_HALF(0, ct);
      COMPUTE_HALF(1, ct);

      if (t < nt2 - 1) {
        asm volatile("s_waitcnt vmcnt(0)" ::: "memory");
        WRITE_V2(cur ^ 1, ct + 1);
        asm volatile("s_waitcnt lgkmcnt(0)" ::: "memory");
        BAR();
        cur ^= 1;
      }
    }
  }

  if (SPLIT) {
    u16* po = outp + (size_t)split * T_SEQ * 2 * 1024;
#pragma unroll
    for (int mt = 0; mt < 2; ++mt) {
#pragma unroll
      for (int r = 0; r < 4; ++r) {
        int q = q0 + mt * 16 + g * 4 + r;
#pragma unroll
        for (int nt = 0; nt < 4; ++nt)
          po[(rowb + q) * 1024 + h * 64 + nt * 16 + r15] = f2bf(accO[mt][nt][r]);
      }
      if (r15 == 0) {
        int idxm = ((split * 2 + b) * 16 + h) * T_SEQ + q0 + mt * 16 + g * 4;
        *(f32x4*)(Ml + idxm) = ssum[mt];
      }
    }
  } else {
#pragma unroll
    for (int mt = 0; mt < 2; ++mt)
#pragma unroll
      for (int r = 0; r < 4; ++r) {
        float inv = 1.f / ssum[mt][r];
        int q = q0 + mt * 16 + g * 4 + r;
#pragma unroll
        for (int nt = 0; nt < 4; ++nt)
          outp[(rowb + q) * 1024 + h * 64 + nt * 16 + r15] =
              f2bf(accO[mt][nt][r] * inv);
      }
  }
#undef ISSUE_K2
#undef LOAD_V2
#undef WRITE_V2
#undef COMPUTE_HALF
}

// ---------------- combine two KV-splits (m=0: just l0+l1) ----------------
__global__ __launch_bounds__(256) void attn_combine(
    const u16* __restrict__ part, const float* __restrict__ Ml,
    u16* __restrict__ att) {
  int idx = blockIdx.x * 256 + threadIdx.x;  // (B*T)*(H/8) = 524288
  int row = idx >> 7;                        // b*2048 + q
  int c8 = idx & 127;
  int col = c8 * 8;
  int h = c8 >> 3;
  int b = row >> 11, q = row & 2047;
  float l0 = Ml[(b * 16 + h) * T_SEQ + q];
  float l1 = Ml[((2 + b) * 16 + h) * T_SEQ + q];
  float inv = 1.f / (l0 + l1);
  bf16x8 o0 = *(const bf16x8*)(part + (size_t)row * 1024 + col);
  bf16x8 o1 = *(const bf16x8*)(part + (size_t)T_SEQ * 2 * 1024 +
                               (size_t)row * 1024 + col);
  bf16x8 o;
#pragma unroll
  for (int j = 0; j < 8; ++j)
    o[j] = (short)f2bf((bf2f((u16)o0[j]) + bf2f((u16)o1[j])) * inv);
  *(bf16x8*)(att + (size_t)row * 1024 + col) = o;
}

// ---------------- launch ----------------
extern "C" void kernel_launch(void* const* d_in, const int* in_sizes, int n_in,
                              void* d_out, int out_size, void* d_ws, size_t ws_size,
                              hipStream_t stream) {
  const float* x = (const float*)d_in[0];     // [2,2048,1024] f32
  const int* mask = (const int*)d_in[1];      // [2,1,1,2048] int32
  const float* Wqkv = (const float*)d_in[2];  // [1024,3072] f32
  const float* bqkv = (const float*)d_in[3];  // [3072] f32
  const float* Wout = (const float*)d_in[4];  // [1024,1024] f32
  const float* bout = (const float*)d_in[5];  // [1024] f32
  float* out = (float*)d_out;                 // [2,2048,1024] f32

  const int B = 2, T = 2048, H = 1024, M = B * T;

  u16* qkv = (u16*)d_ws;                       // M*3H
  u16* att = qkv + (size_t)M * 3 * H;          // M*H
  u16* WtQ = att + (size_t)M * H;              // 3H*H
  u16* WtO = WtQ + (size_t)3 * H * H;          // H*H
  u16* part = WtO + (size_t)H * H;             // 2 * M*H  (split partials)
  float* Ml = (float*)(part + (size_t)2 * M * H);  // 2*131072 floats
  int* idxb = (int*)(Ml + (size_t)2 * 131072);     // B*T ints
  int* cntb = idxb + B * T;                        // B ints

  const size_t need = ((size_t)M * 3 * H + (size_t)M * H + (size_t)3 * H * H +
                       (size_t)H * H + (size_t)2 * M * H) * 2 +
                      (size_t)2 * 131072 * 4 + (size_t)(B * T + 8) * 4;
  const bool split = ws_size >= need;

  transpose_f32_bf16<<<dim3(3 * H / 32, H / 32), 256, 0, stream>>>(Wqkv, WtQ, H, 3 * H);
  transpose_f32_bf16<<<dim3(H / 32, H / 32), 256, 0, stream>>>(Wout, WtO, H, H);
  mask_compact<<<B, 512, 0, stream>>>(mask, idxb, cntb);
  gemm_a32_bf16<<<(3 * H / 128) * (M / 128), 256, 0, stream>>>(x, WtQ, bqkv, qkv, M, 3 * H, H);
  if (split) {
    attn_fwd<true><<<512, 512, 0, stream>>>(qkv, idxb, cntb, part, Ml);
    attn_combine<<<(M * H / 8 + 255) / 256, 256, 0, stream>>>(part, Ml, att);
  } else {
    attn_fwd<false><<<256, 512, 0, stream>>>(qkv, idxb, cntb, att, Ml);
  }
  gemm_bf16<false><<<(H / 128) * (M / 128), 256, 0, stream>>>(att, WtO, bout, out, M, H, H);
}

// Round 18
// 120.282 us; speedup vs baseline: 1.2600x; 1.2600x over previous
//
#include <hip/hip_runtime.h>
#include <stdint.h>

typedef unsigned short u16;
typedef unsigned int u32;
typedef short bf16x8 __attribute__((ext_vector_type(8)));
typedef float f32x4 __attribute__((ext_vector_type(4)));

#define MFMA16(a, b, c) __builtin_amdgcn_mfma_f32_16x16x32_bf16((a), (b), (c), 0, 0, 0)
#define BAR()                              \
  do {                                     \
    __builtin_amdgcn_sched_barrier(0);     \
    __builtin_amdgcn_s_barrier();          \
    __builtin_amdgcn_sched_barrier(0);     \
  } while (0)

__device__ __forceinline__ u16 f2bf(float f) {
  union { float f; u32 u; } v; v.f = f;
  u32 u = v.u;
  u32 r = (u + 0x7FFFu + ((u >> 16) & 1u)) >> 16;  // RNE
  return (u16)r;
}
__device__ __forceinline__ float bf2f(u16 h) {
  union { u32 u; float f; } v; v.u = ((u32)h) << 16;
  return v.f;
}
// packed f32x2 -> bf16x2 (single HW instruction, RNE)
__device__ __forceinline__ u32 cvtpk_bf16(float lo, float hi) {
  u32 r;
  asm("v_cvt_pk_bf16_f32 %0, %1, %2" : "=v"(r) : "v"(lo), "v"(hi));
  return r;
}

// async global->LDS, 16B per lane. LDS base must be wave-uniform (HW adds lane*16).
__device__ __forceinline__ void gload_lds16(const void* g, void* l) {
  __builtin_amdgcn_global_load_lds(
      (const __attribute__((address_space(1))) unsigned int*)g,
      (__attribute__((address_space(3))) unsigned int*)l,
      16, 0, 0);
}

// ---------------- transpose+convert: src f32 [R][C] -> dst bf16 [C][R] ----------------
__global__ __launch_bounds__(256) void transpose_f32_bf16(
    const float* __restrict__ src, u16* __restrict__ dst, int R, int C) {
  __shared__ u16 t[32][33];
  const int bx = blockIdx.x * 32, by = blockIdx.y * 32;
  const int tx = threadIdx.x & 31, ty = threadIdx.x >> 5;  // 32x8
#pragma unroll
  for (int i = 0; i < 32; i += 8)
    t[ty + i][tx] = f2bf(src[(size_t)(by + ty + i) * C + bx + tx]);
  __syncthreads();
#pragma unroll
  for (int i = 0; i < 32; i += 8)
    dst[(size_t)(bx + ty + i) * R + by + tx] = t[tx][ty + i];
}

// ---------------- mask compaction: idx[b][] = unmasked key positions ----------------
__global__ __launch_bounds__(512) void mask_compact(
    const int* __restrict__ mask, int* __restrict__ idx, int* __restrict__ cnt) {
  const int b = blockIdx.x;
  const int tid = threadIdx.x;
  const int lane = tid & 63, wave = tid >> 6;
  __shared__ int wtot[8];
  int m[4], c = 0;
#pragma unroll
  for (int j = 0; j < 4; ++j) {
    m[j] = (mask[b * 2048 + tid * 4 + j] != 0);
    c += m[j];
  }
  int pfx = c;
#pragma unroll
  for (int sh = 1; sh < 64; sh <<= 1) {
    int v = __shfl_up(pfx, sh);
    if (lane >= sh) pfx += v;
  }
  if (lane == 63) wtot[wave] = pfx;
  int epfx = pfx - c;
  __syncthreads();
  int wbase = 0, total = 0;
#pragma unroll
  for (int w = 0; w < 8; ++w) {
    int v = wtot[w];
    if (w < wave) wbase += v;
    total += v;
  }
  int pos = b * 2048 + wbase + epfx;
#pragma unroll
  for (int j = 0; j < 4; ++j)
    if (m[j]) idx[pos++] = tid * 4 + j;
  for (int i = total + tid; i < 2048; i += 512) idx[b * 2048 + i] = 0;
  if (tid == 0) cnt[b] = total;
}

// ------- qkv GEMM, fused f32->bf16 A, 48KB LDS -> 3 blocks/CU (no tail wave) -------
// As single-buffered (16KB) + Bs double (32KB) = 48KB: all 768 blocks co-resident
// (256 CU x 3). Two barriers per step: MFMA(t) -> BAR (As readers done) ->
// cvt A(t+1)->As (counted A-reg wait; in-order vmcnt => B(t+1) landed) -> BAR.
// A(t+1)/B(t+1) issued BEFORE MFMA(t) so ~1 MFMA phase + cross-block TLP (12
// waves/CU) covers the HBM latency. Round-17 lesson: depth-2 blew VGPR/LDS/L2.
__global__ __launch_bounds__(256) void gemm_a32_bf16(
    const float* __restrict__ A, const u16* __restrict__ Bt,
    const float* __restrict__ bias, u16* __restrict__ Cout,
    int M, int N, int K) {
  __shared__ __align__(16) u16 As[128 * 64];
  __shared__ __align__(16) u16 Bs[2][128 * 64];
  const int tid = threadIdx.x;
  const int lane = tid & 63;
  const int wave = tid >> 6;
  const int nwg = gridDim.x;
  const int id = blockIdx.x;
  const int sw = (id & 7) * (nwg >> 3) + (id >> 3);
  const int nx = N >> 7;
  const int m0 = (sw / nx) * 128;
  const int n0 = (sw % nx) * 128;
  const int wm = (wave >> 1) * 64;
  const int wn = (wave & 1) * 64;

  f32x4 acc[4][4] = {};
  const char* Bbase = (const char*)Bt;
  float4 fa[4], fb[4];

#define A32_ISSUE_B(ktile, buf)                                                \
  _Pragma("unroll") for (int i = 0; i < 4; ++i) {                              \
    int flat = wave * 1024 + lane * 16 + i * 4096;                             \
    int row = flat >> 7;                                                       \
    int cb = flat & 127;                                                       \
    int scb = cb ^ ((row & 7) << 4);                                           \
    gload_lds16(Bbase + ((size_t)(n0 + row) * K + (ktile)) * 2 + scb,          \
                (char*)&Bs[buf][0] + flat);                                    \
  }

#define A32_LOAD_A(ktile)                                                      \
  _Pragma("unroll") for (int i = 0; i < 4; ++i) {                              \
    int flat = wave * 1024 + lane * 16 + i * 4096;                             \
    int row = flat >> 7;                                                       \
    int cb = flat & 127;                                                       \
    const float* ax = A + (size_t)(m0 + row) * K + (ktile) + (cb >> 1);        \
    fa[i] = *(const float4*)ax;                                                \
    fb[i] = *(const float4*)(ax + 4);                                          \
  }

#define A32_CVT()                                                              \
  _Pragma("unroll") for (int i = 0; i < 4; ++i) {                              \
    int flat = wave * 1024 + lane * 16 + i * 4096;                             \
    int row = flat >> 7;                                                       \
    int cb = flat & 127;                                                       \
    union { u32 w[4]; bf16x8 v; } o;                                           \
    o.w[0] = cvtpk_bf16(fa[i].x, fa[i].y);                                     \
    o.w[1] = cvtpk_bf16(fa[i].z, fa[i].w);                                     \
    o.w[2] = cvtpk_bf16(fb[i].x, fb[i].y);                                     \
    o.w[3] = cvtpk_bf16(fb[i].z, fb[i].w);                                     \
    *(bf16x8*)((char*)&As[0] + row * 128 + (cb ^ ((row & 7) << 4))) = o.v;     \
  }

  // prologue: B(0) then A(0) (order matters: A-wait implies B landed)
  A32_ISSUE_B(0, 0);
  A32_LOAD_A(0);
  A32_CVT();
  asm volatile("s_waitcnt lgkmcnt(0)" ::: "memory");
  BAR();

  const int nsteps = K >> 6;
  for (int t = 0; t < nsteps; ++t) {
    if (t < nsteps - 1) {
      A32_ISSUE_B((t << 6) + 64, (t & 1) ^ 1);
      A32_LOAD_A((t << 6) + 64);
    }
    __builtin_amdgcn_sched_barrier(0);  // issues stay above MFMA
#pragma unroll
    for (int ks = 0; ks < 2; ++ks) {
      const int col = (lane >> 4) * 8 + ks * 32;
      bf16x8 af[4], bfr[4];
#pragma unroll
      for (int mt = 0; mt < 4; ++mt) {
        int row = wm + mt * 16 + (lane & 15);
        af[mt] = *(const bf16x8*)((const char*)&As[0] + row * 128 +
                                  ((col * 2) ^ ((row & 7) << 4)));
      }
#pragma unroll
      for (int nt = 0; nt < 4; ++nt) {
        int row = wn + nt * 16 + (lane & 15);
        bfr[nt] = *(const bf16x8*)((const char*)&Bs[t & 1][0] + row * 128 +
                                   ((col * 2) ^ ((row & 7) << 4)));
      }
#pragma unroll
      for (int mt = 0; mt < 4; ++mt)
#pragma unroll
        for (int nt = 0; nt < 4; ++nt)
          acc[mt][nt] = MFMA16(af[mt], bfr[nt], acc[mt][nt]);
    }
    __builtin_amdgcn_sched_barrier(0);  // cvt stays below MFMA
    if (t < nsteps - 1) {
      BAR();     // all waves done reading As(t)
      A32_CVT();  // write As(t+1); counted wait on A(t+1) regs => B(t+1) landed
      asm volatile("s_waitcnt lgkmcnt(0)" ::: "memory");
      BAR();     // As(t+1)/Bs(t+1) visible to all
    }
  }
#undef A32_ISSUE_B
#undef A32_LOAD_A
#undef A32_CVT

  float bv[4];
#pragma unroll
  for (int nt = 0; nt < 4; ++nt)
    bv[nt] = bias[n0 + wn + nt * 16 + (lane & 15)];
#pragma unroll
  for (int mt = 0; mt < 4; ++mt)
#pragma unroll
    for (int nt = 0; nt < 4; ++nt)
#pragma unroll
      for (int r = 0; r < 4; ++r) {
        int m = m0 + wm + mt * 16 + (lane >> 4) * 4 + r;
        int n = n0 + wn + nt * 16 + (lane & 15);
        Cout[(size_t)m * N + n] = f2bf(acc[mt][nt][r] + bv[nt]);
      }
}

// ---------------- GEMM (bf16 A), pipelined dbuf + T2 swizzle ----------------
template <bool OUT_BF16>
__global__ __launch_bounds__(256) void gemm_bf16(
    const u16* __restrict__ A, const u16* __restrict__ Bt,
    const float* __restrict__ bias, void* __restrict__ Cout,
    int M, int N, int K) {
  __shared__ __align__(16) u16 As[2][128 * 64];
  __shared__ __align__(16) u16 Bs[2][128 * 64];
  const int tid = threadIdx.x;
  const int lane = tid & 63;
  const int wave = tid >> 6;
  const int nwg = gridDim.x;
  const int id = blockIdx.x;
  const int sw = (id & 7) * (nwg >> 3) + (id >> 3);
  const int nx = N >> 7;
  const int m0 = (sw / nx) * 128;
  const int n0 = (sw % nx) * 128;
  const int wm = (wave >> 1) * 64;
  const int wn = (wave & 1) * 64;

  f32x4 acc[4][4] = {};

  const char* Abase = (const char*)A;
  const char* Bbase = (const char*)Bt;

#define STAGE_AB(ktile, buf)                                                   \
  _Pragma("unroll") for (int i = 0; i < 4; ++i) {                              \
    int flat = wave * 1024 + lane * 16 + i * 4096;                             \
    int row = flat >> 7;                                                       \
    int cb = flat & 127;                                                       \
    int scb = cb ^ ((row & 7) << 4);                                           \
    gload_lds16(Abase + ((size_t)(m0 + row) * K + (ktile)) * 2 + scb,          \
                (char*)&As[buf][0] + flat);                                    \
    gload_lds16(Bbase + ((size_t)(n0 + row) * K + (ktile)) * 2 + scb,          \
                (char*)&Bs[buf][0] + flat);                                    \
  }

  STAGE_AB(0, 0);

  const int nsteps = K >> 6;
  for (int t = 0; t < nsteps; ++t) {
    asm volatile("s_waitcnt vmcnt(0)" ::: "memory");
    BAR();
    if (t < nsteps - 1) STAGE_AB((t << 6) + 64, (t & 1) ^ 1);
#pragma unroll
    for (int ks = 0; ks < 2; ++ks) {
      const int col = (lane >> 4) * 8 + ks * 32;
      bf16x8 af[4], bfr[4];
#pragma unroll
      for (int mt = 0; mt < 4; ++mt) {
        int row = wm + mt * 16 + (lane & 15);
        af[mt] = *(const bf16x8*)((const char*)&As[t & 1][0] + row * 128 +
                                  ((col * 2) ^ ((row & 7) << 4)));
      }
#pragma unroll
      for (int nt = 0; nt < 4; ++nt) {
        int row = wn + nt * 16 + (lane & 15);
        bfr[nt] = *(const bf16x8*)((const char*)&Bs[t & 1][0] + row * 128 +
                                   ((col * 2) ^ ((row & 7) << 4)));
      }
#pragma unroll
      for (int mt = 0; mt < 4; ++mt)
#pragma unroll
        for (int nt = 0; nt < 4; ++nt)
          acc[mt][nt] = MFMA16(af[mt], bfr[nt], acc[mt][nt]);
    }
  }
#undef STAGE_AB

  float bv[4];
#pragma unroll
  for (int nt = 0; nt < 4; ++nt)
    bv[nt] = bias[n0 + wn + nt * 16 + (lane & 15)];
#pragma unroll
  for (int mt = 0; mt < 4; ++mt)
#pragma unroll
    for (int nt = 0; nt < 4; ++nt)
#pragma unroll
      for (int r = 0; r < 4; ++r) {
        int m = m0 + wm + mt * 16 + (lane >> 4) * 4 + r;
        int n = n0 + wn + nt * 16 + (lane & 15);
        float v = acc[mt][nt][r] + bv[nt];
        if (OUT_BF16)
          ((u16*)Cout)[(size_t)m * N + n] = f2bf(v);
        else
          ((float*)Cout)[(size_t)m * N + n] = v;
      }
}

// ---------------- flash attention (v13: COMPACTED keys via idx gather) ----------
// UNCHANGED (~40 us; compaction halves all attention work).
#define T_SEQ 2048
#define ROWQKV 3072
#define SCL 0.180336880f  /* (1/sqrt(64)) * log2(e) */

template <bool SPLIT>
__global__ __launch_bounds__(512) void attn_fwd(
    const u16* __restrict__ qkv, const int* __restrict__ idx,
    const int* __restrict__ cnt, u16* __restrict__ outp,
    float* __restrict__ Ml) {
  __shared__ __align__(16) u16 Ks[2][2][64 * 64];  // [buf][half][storerow][dk], swz s=row&7
  __shared__ __align__(16) u16 Vt[2][2][64 * 64];  // [buf][half][d][cpos], swz row^(row>>3)
  __shared__ __align__(16) u32 lut[256 * 4];       // byte -> 8 x bf16 {0,1}

  const int tid = threadIdx.x;
  const int lane = tid & 63;
  const int wave = tid >> 6;
  const int r15 = lane & 15;
  const int g = lane >> 4;
  const int id = blockIdx.x;
  const int hz = ((id >> 6) << 3) | (id & 7);
  const int qb = (id >> 3) & 7;
  const int h = SPLIT ? (hz >> 2) : (hz >> 1);
  const int z = SPLIT ? (hz & 3) : (hz & 1);
  const int split = SPLIT ? (z >> 1) : 0;
  const int b = SPLIT ? (z & 1) : z;
  const int q0 = qb * 256 + wave * 32;
  const size_t rowb = (size_t)b * T_SEQ;
  const int* idxb = idx + b * 2048;
  const int count = cnt[b];
  const int ntot = (count + 127) >> 7;
  const int nth = (ntot + 1) >> 1;
  const int t0 = (SPLIT && split) ? nth : 0;
  const int nt2 = SPLIT ? (split ? ntot - nth : nth) : ntot;

  for (int i = tid; i < 256; i += 512) {
    union { u32 w[4]; bf16x8 v; } e;
#pragma unroll
    for (int j = 0; j < 4; ++j)
      e.w[j] = (((i >> (2 * j)) & 1) ? 0x3F80u : 0u) |
               (((i >> (2 * j + 1)) & 1) ? 0x3F800000u : 0u);
    *(bf16x8*)((char*)lut + i * 16) = e.v;
  }

  bf16x8 aq[2][2];
#pragma unroll
  for (int mt = 0; mt < 2; ++mt)
#pragma unroll
    for (int ks = 0; ks < 2; ++ks) {
      bf16x8 t = *(const bf16x8*)(qkv +
          (rowb + q0 + mt * 16 + r15) * ROWQKV + h * 64 + g * 8 + ks * 32);
#pragma unroll
      for (int j = 0; j < 8; ++j) t[j] = (short)f2bf(bf2f((u16)t[j]) * SCL);
      aq[mt][ks] = t;
    }

  f32x4 accO[2][4] = {};
  f32x4 ssum[2] = {};
  bf16x8 vr0, vr1;

#define ISSUE_K2(ct, buf)                                                      \
  {                                                                            \
    int L = wave * 1024 + lane * 16;                                           \
    int row = L >> 7;                                                          \
    int cb = L & 127;                                                          \
    int scb = cb ^ ((row & 7) << 4);                                           \
    int prow = ((row >> 4) & 1) * 32 + ((row >> 2) & 3) * 8 +                  \
               (row >> 5) * 4 + (row & 3);                                     \
    int gk0 = idxb[(ct) * 128 + prow];                                         \
    int gk1 = idxb[(ct) * 128 + 64 + prow];                                    \
    gload_lds16((const char*)qkv +                                             \
                    ((rowb + gk0) * ROWQKV + 1024 + h * 64) * 2 + scb,         \
                (char*)&Ks[buf][0][0] + wave * 1024);                          \
    gload_lds16((const char*)qkv +                                             \
                    ((rowb + gk1) * ROWQKV + 1024 + h * 64) * 2 + scb,         \
                (char*)&Ks[buf][1][0] + wave * 1024);                          \
  }

#define LOAD_V2(ct)                                                            \
  {                                                                            \
    int key = tid >> 3;                                                        \
    int gv0 = idxb[(ct) * 128 + key];                                          \
    int gv1 = idxb[(ct) * 128 + 64 + key];                                     \
    vr0 = *(const bf16x8*)(qkv + (rowb + gv0) * ROWQKV + 2048 + h * 64 +       \
                           (tid & 7) * 8);                                     \
    vr1 = *(const bf16x8*)(qkv + (rowb + gv1) * ROWQKV + 2048 + h * 64 +       \
                           (tid & 7) * 8);                                     \
  }

#define WRITE_V2(buf, ct)                                                      \
  {                                                                            \
    int key = tid >> 3;                                                        \
    if ((ct) * 128 + key >= count) {                                           \
      bf16x8 zz = {};                                                          \
      vr0 = zz;                                                                \
    }                                                                          \
    if ((ct) * 128 + 64 + key >= count) {                                      \
      bf16x8 zz = {};                                                          \
      vr1 = zz;                                                                \
    }                                                                          \
    _Pragma("unroll") for (int j = 0; j < 8; ++j) {                            \
      int row = (tid & 7) * 8 + j;                                             \
      int sv = ((row ^ (row >> 3)) & 7) << 4;                                  \
      *(u16*)((char*)&Vt[buf][0][0] + row * 128 + ((key * 2) ^ sv)) =          \
          (u16)vr0[j];                                                         \
      *(u16*)((char*)&Vt[buf][1][0] + row * 128 + ((key * 2) ^ sv)) =          \
          (u16)vr1[j];                                                         \
    }                                                                          \
  }

#define COMPUTE_HALF(H, ct)                                                    \
  {                                                                            \
    f32x4 s[2][4] = {};                                                        \
    _Pragma("unroll") for (int ks = 0; ks < 2; ++ks) {                         \
      bf16x8 bk[4];                                                            \
      _Pragma("unroll") for (int nt = 0; nt < 4; ++nt) {                       \
        int row = nt * 16 + r15;                                               \
        int cb = (g * 8 + ks * 32) * 2;                                        \
        bk[nt] = *(const bf16x8*)((const char*)&Ks[cur][H][0] + row * 128 +    \
                                  (cb ^ ((row & 7) << 4)));                    \
      }                                                                        \
      _Pragma("unroll") for (int mt = 0; mt < 2; ++mt)                         \
        _Pragma("unroll") for (int nt = 0; nt < 4; ++nt)                       \
          s[mt][nt] = MFMA16(bk[nt], aq[mt][ks], s[mt][nt]);                   \
    }                                                                          \
    u32 pk[2][4][2];                                                           \
    _Pragma("unroll") for (int mt = 0; mt < 2; ++mt)                           \
      _Pragma("unroll") for (int nt = 0; nt < 4; ++nt) {                       \
        float e0 = exp2f(s[mt][nt][0]);                                        \
        float e1 = exp2f(s[mt][nt][1]);                                        \
        float e2 = exp2f(s[mt][nt][2]);                                        \
        float e3 = exp2f(s[mt][nt][3]);                                        \
        pk[mt][nt][0] = cvtpk_bf16(e0, e1);                                    \
        pk[mt][nt][1] = cvtpk_bf16(e2, e3);                                    \
      }                                                                        \
    __builtin_amdgcn_s_setprio(1);                                             \
    _Pragma("unroll") for (int ks = 0; ks < 2; ++ks) {                         \
      const int col = g * 8 + ks * 32;                                         \
      bf16x8 bv[4];                                                            \
      _Pragma("unroll") for (int nt = 0; nt < 4; ++nt) {                       \
        int row = nt * 16 + r15;                                               \
        int sv = ((row ^ (row >> 3)) & 7) << 4;                                \
        bv[nt] = *(const bf16x8*)((const char*)&Vt[cur][H][0] + row * 128 +    \
                                  ((col * 2) ^ sv));                           \
      }                                                                        \
      int rbase = count - ((ct) * 128 + (H) * 64 + ks * 32 + g * 8);           \
      int rr = rbase < 0 ? 0 : (rbase > 8 ? 8 : rbase);                        \
      u32 lb = (1u << rr) - 1u;                                                \
      bf16x8 mf = *(const bf16x8*)((const char*)lut + lb * 16);                \
      _Pragma("unroll") for (int mt = 0; mt < 2; ++mt) {                       \
        union { u32 w[4]; bf16x8 v; } ap;                                      \
        ap.w[0] = pk[mt][ks][0];                                               \
        ap.w[1] = pk[mt][ks][1];                                               \
        ap.w[2] = pk[mt][2 + ks][0];                                           \
        ap.w[3] = pk[mt][2 + ks][1];                                           \
        _Pragma("unroll") for (int nt = 0; nt < 4; ++nt)                       \
          accO[mt][nt] = MFMA16(ap.v, bv[nt], accO[mt][nt]);                   \
        ssum[mt] = MFMA16(ap.v, mf, ssum[mt]);                                 \
      }                                                                        \
    }                                                                          \
    __builtin_amdgcn_s_setprio(0);                                             \
  }

  if (nt2 > 0) {
    ISSUE_K2(t0, 0);
    LOAD_V2(t0);
    __syncthreads();
    WRITE_V2(0, t0);
    asm volatile("s_waitcnt lgkmcnt(0)" ::: "memory");
    BAR();

    int cur = 0;
    for (int t = 0; t < nt2; ++t) {
      const int ct = t0 + t;
      if (t < nt2 - 1) {
        ISSUE_K2(ct + 1, cur ^ 1);
        LOAD_V2(ct + 1);
      }

      COMPUTE_HALF(0, ct);
      COMPUTE_HALF(1, ct);

      if (t < nt2 - 1) {
        asm volatile("s_waitcnt vmcnt(0)" ::: "memory");
        WRITE_V2(cur ^ 1, ct + 1);
        asm volatile("s_waitcnt lgkmcnt(0)" ::: "memory");
        BAR();
        cur ^= 1;
      }
    }
  }

  if (SPLIT) {
    u16* po = outp + (size_t)split * T_SEQ * 2 * 1024;
#pragma unroll
    for (int mt = 0; mt < 2; ++mt) {
#pragma unroll
      for (int r = 0; r < 4; ++r) {
        int q = q0 + mt * 16 + g * 4 + r;
#pragma unroll
        for (int nt = 0; nt < 4; ++nt)
          po[(rowb + q) * 1024 + h * 64 + nt * 16 + r15] = f2bf(accO[mt][nt][r]);
      }
      if (r15 == 0) {
        int idxm = ((split * 2 + b) * 16 + h) * T_SEQ + q0 + mt * 16 + g * 4;
        *(f32x4*)(Ml + idxm) = ssum[mt];
      }
    }
  } else {
#pragma unroll
    for (int mt = 0; mt < 2; ++mt)
#pragma unroll
      for (int r = 0; r < 4; ++r) {
        float inv = 1.f / ssum[mt][r];
        int q = q0 + mt * 16 + g * 4 + r;
#pragma unroll
        for (int nt = 0; nt < 4; ++nt)
          outp[(rowb + q) * 1024 + h * 64 + nt * 16 + r15] =
              f2bf(accO[mt][nt][r] * inv);
      }
  }
#undef ISSUE_K2
#undef LOAD_V2
#undef WRITE_V2
#undef COMPUTE_HALF
}

// ---------------- combine two KV-splits (m=0: just l0+l1) ----------------
__global__ __launch_bounds__(256) void attn_combine(
    const u16* __restrict__ part, const float* __restrict__ Ml,
    u16* __restrict__ att) {
  int idx = blockIdx.x * 256 + threadIdx.x;  // (B*T)*(H/8) = 524288
  int row = idx >> 7;                        // b*2048 + q
  int c8 = idx & 127;
  int col = c8 * 8;
  int h = c8 >> 3;
  int b = row >> 11, q = row & 2047;
  float l0 = Ml[(b * 16 + h) * T_SEQ + q];
  float l1 = Ml[((2 + b) * 16 + h) * T_SEQ + q];
  float inv = 1.f / (l0 + l1);
  bf16x8 o0 = *(const bf16x8*)(part + (size_t)row * 1024 + col);
  bf16x8 o1 = *(const bf16x8*)(part + (size_t)T_SEQ * 2 * 1024 +
                               (size_t)row * 1024 + col);
  bf16x8 o;
#pragma unroll
  for (int j = 0; j < 8; ++j)
    o[j] = (short)f2bf((bf2f((u16)o0[j]) + bf2f((u16)o1[j])) * inv);
  *(bf16x8*)(att + (size_t)row * 1024 + col) = o;
}

// ---------------- launch ----------------
extern "C" void kernel_launch(void* const* d_in, const int* in_sizes, int n_in,
                              void* d_out, int out_size, void* d_ws, size_t ws_size,
                              hipStream_t stream) {
  const float* x = (const float*)d_in[0];     // [2,2048,1024] f32
  const int* mask = (const int*)d_in[1];      // [2,1,1,2048] int32
  const float* Wqkv = (const float*)d_in[2];  // [1024,3072] f32
  const float* bqkv = (const float*)d_in[3];  // [3072] f32
  const float* Wout = (const float*)d_in[4];  // [1024,1024] f32
  const float* bout = (const float*)d_in[5];  // [1024] f32
  float* out = (float*)d_out;                 // [2,2048,1024] f32

  const int B = 2, T = 2048, H = 1024, M = B * T;

  u16* qkv = (u16*)d_ws;                       // M*3H
  u16* att = qkv + (size_t)M * 3 * H;          // M*H
  u16* WtQ = att + (size_t)M * H;              // 3H*H
  u16* WtO = WtQ + (size_t)3 * H * H;          // H*H
  u16* part = WtO + (size_t)H * H;             // 2 * M*H  (split partials)
  float* Ml = (float*)(part + (size_t)2 * M * H);  // 2*131072 floats
  int* idxb = (int*)(Ml + (size_t)2 * 131072);     // B*T ints
  int* cntb = idxb + B * T;                        // B ints

  const size_t need = ((size_t)M * 3 * H + (size_t)M * H + (size_t)3 * H * H +
                       (size_t)H * H + (size_t)2 * M * H) * 2 +
                      (size_t)2 * 131072 * 4 + (size_t)(B * T + 8) * 4;
  const bool split = ws_size >= need;

  transpose_f32_bf16<<<dim3(3 * H / 32, H / 32), 256, 0, stream>>>(Wqkv, WtQ, H, 3 * H);
  transpose_f32_bf16<<<dim3(H / 32, H / 32), 256, 0, stream>>>(Wout, WtO, H, H);
  mask_compact<<<B, 512, 0, stream>>>(mask, idxb, cntb);
  gemm_a32_bf16<<<(3 * H / 128) * (M / 128), 256, 0, stream>>>(x, WtQ, bqkv, qkv, M, 3 * H, H);
  if (split) {
    attn_fwd<true><<<512, 512, 0, stream>>>(qkv, idxb, cntb, part, Ml);
    attn_combine<<<(M * H / 8 + 255) / 256, 256, 0, stream>>>(part, Ml, att);
  } else {
    attn_fwd<false><<<256, 512, 0, stream>>>(qkv, idxb, cntb, att, Ml);
  }
  gemm_bf16<false><<<(H / 128) * (M / 128), 256, 0, stream>>>(att, WtO, bout, out, M, H, H);
}

// Round 19
// 117.524 us; speedup vs baseline: 1.2895x; 1.0235x over previous
//
#include <hip/hip_runtime.h>
#include <stdint.h>

typedef unsigned short u16;
typedef unsigned int u32;
typedef short bf16x8 __attribute__((ext_vector_type(8)));
typedef float f32x4 __attribute__((ext_vector_type(4)));

#define MFMA16(a, b, c) __builtin_amdgcn_mfma_f32_16x16x32_bf16((a), (b), (c), 0, 0, 0)
#define BAR()                              \
  do {                                     \
    __builtin_amdgcn_sched_barrier(0);     \
    __builtin_amdgcn_s_barrier();          \
    __builtin_amdgcn_sched_barrier(0);     \
  } while (0)

__device__ __forceinline__ u16 f2bf(float f) {
  union { float f; u32 u; } v; v.f = f;
  u32 u = v.u;
  u32 r = (u + 0x7FFFu + ((u >> 16) & 1u)) >> 16;  // RNE
  return (u16)r;
}
__device__ __forceinline__ float bf2f(u16 h) {
  union { u32 u; float f; } v; v.u = ((u32)h) << 16;
  return v.f;
}
// packed f32x2 -> bf16x2 (single HW instruction, RNE)
__device__ __forceinline__ u32 cvtpk_bf16(float lo, float hi) {
  u32 r;
  asm("v_cvt_pk_bf16_f32 %0, %1, %2" : "=v"(r) : "v"(lo), "v"(hi));
  return r;
}

// async global->LDS, 16B per lane. LDS base must be wave-uniform (HW adds lane*16).
__device__ __forceinline__ void gload_lds16(const void* g, void* l) {
  __builtin_amdgcn_global_load_lds(
      (const __attribute__((address_space(1))) unsigned int*)g,
      (__attribute__((address_space(3))) unsigned int*)l,
      16, 0, 0);
}

// ------- fused weight transposes: Wqkv (1024x3072) + Wout (1024x1024), one launch -------
__global__ __launch_bounds__(256) void transpose_weights(
    const float* __restrict__ Wqkv, u16* __restrict__ WtQ,
    const float* __restrict__ Wout, u16* __restrict__ WtO) {
  __shared__ u16 t[32][33];
  int id = blockIdx.x;
  const float* src;
  u16* dst;
  int C, bx, by;
  if (id < 3072) {  // Wqkv: 96 x 32 tiles
    src = Wqkv; dst = WtQ; C = 3072;
    bx = (id % 96) * 32; by = (id / 96) * 32;
  } else {          // Wout: 32 x 32 tiles
    id -= 3072;
    src = Wout; dst = WtO; C = 1024;
    bx = (id % 32) * 32; by = (id / 32) * 32;
  }
  const int R = 1024;
  const int tx = threadIdx.x & 31, ty = threadIdx.x >> 5;  // 32x8
#pragma unroll
  for (int i = 0; i < 32; i += 8)
    t[ty + i][tx] = f2bf(src[(size_t)(by + ty + i) * C + bx + tx]);
  __syncthreads();
#pragma unroll
  for (int i = 0; i < 32; i += 8)
    dst[(size_t)(bx + ty + i) * R + by + tx] = t[tx][ty + i];
}

// ---------------- mask compaction: idx[b][] = unmasked key positions ----------------
__global__ __launch_bounds__(512) void mask_compact(
    const int* __restrict__ mask, int* __restrict__ idx, int* __restrict__ cnt) {
  const int b = blockIdx.x;
  const int tid = threadIdx.x;
  const int lane = tid & 63, wave = tid >> 6;
  __shared__ int wtot[8];
  int m[4], c = 0;
#pragma unroll
  for (int j = 0; j < 4; ++j) {
    m[j] = (mask[b * 2048 + tid * 4 + j] != 0);
    c += m[j];
  }
  int pfx = c;
#pragma unroll
  for (int sh = 1; sh < 64; sh <<= 1) {
    int v = __shfl_up(pfx, sh);
    if (lane >= sh) pfx += v;
  }
  if (lane == 63) wtot[wave] = pfx;
  int epfx = pfx - c;
  __syncthreads();
  int wbase = 0, total = 0;
#pragma unroll
  for (int w = 0; w < 8; ++w) {
    int v = wtot[w];
    if (w < wave) wbase += v;
    total += v;
  }
  int pos = b * 2048 + wbase + epfx;
#pragma unroll
  for (int j = 0; j < 4; ++j)
    if (m[j]) idx[pos++] = tid * 4 + j;
  for (int i = total + tid; i < 2048; i += 512) idx[b * 2048 + i] = 0;
  if (tid == 0) cnt[b] = total;
}

// ------- qkv GEMM, fused f32->bf16 A, 48KB LDS -> 3 blocks/CU (no tail wave) -------
__global__ __launch_bounds__(256) void gemm_a32_bf16(
    const float* __restrict__ A, const u16* __restrict__ Bt,
    const float* __restrict__ bias, u16* __restrict__ Cout,
    int M, int N, int K) {
  __shared__ __align__(16) u16 As[128 * 64];
  __shared__ __align__(16) u16 Bs[2][128 * 64];
  const int tid = threadIdx.x;
  const int lane = tid & 63;
  const int wave = tid >> 6;
  const int nwg = gridDim.x;
  const int id = blockIdx.x;
  const int sw = (id & 7) * (nwg >> 3) + (id >> 3);
  const int nx = N >> 7;
  const int m0 = (sw / nx) * 128;
  const int n0 = (sw % nx) * 128;
  const int wm = (wave >> 1) * 64;
  const int wn = (wave & 1) * 64;

  f32x4 acc[4][4] = {};
  const char* Bbase = (const char*)Bt;
  float4 fa[4], fb[4];

#define A32_ISSUE_B(ktile, buf)                                                \
  _Pragma("unroll") for (int i = 0; i < 4; ++i) {                              \
    int flat = wave * 1024 + lane * 16 + i * 4096;                             \
    int row = flat >> 7;                                                       \
    int cb = flat & 127;                                                       \
    int scb = cb ^ ((row & 7) << 4);                                           \
    gload_lds16(Bbase + ((size_t)(n0 + row) * K + (ktile)) * 2 + scb,          \
                (char*)&Bs[buf][0] + flat);                                    \
  }

#define A32_LOAD_A(ktile)                                                      \
  _Pragma("unroll") for (int i = 0; i < 4; ++i) {                              \
    int flat = wave * 1024 + lane * 16 + i * 4096;                             \
    int row = flat >> 7;                                                       \
    int cb = flat & 127;                                                       \
    const float* ax = A + (size_t)(m0 + row) * K + (ktile) + (cb >> 1);        \
    fa[i] = *(const float4*)ax;                                                \
    fb[i] = *(const float4*)(ax + 4);                                          \
  }

#define A32_CVT()                                                              \
  _Pragma("unroll") for (int i = 0; i < 4; ++i) {                              \
    int flat = wave * 1024 + lane * 16 + i * 4096;                             \
    int row = flat >> 7;                                                       \
    int cb = flat & 127;                                                       \
    union { u32 w[4]; bf16x8 v; } o;                                           \
    o.w[0] = cvtpk_bf16(fa[i].x, fa[i].y);                                     \
    o.w[1] = cvtpk_bf16(fa[i].z, fa[i].w);                                     \
    o.w[2] = cvtpk_bf16(fb[i].x, fb[i].y);                                     \
    o.w[3] = cvtpk_bf16(fb[i].z, fb[i].w);                                     \
    *(bf16x8*)((char*)&As[0] + row * 128 + (cb ^ ((row & 7) << 4))) = o.v;     \
  }

  A32_ISSUE_B(0, 0);
  A32_LOAD_A(0);
  A32_CVT();
  asm volatile("s_waitcnt lgkmcnt(0)" ::: "memory");
  BAR();

  const int nsteps = K >> 6;
  for (int t = 0; t < nsteps; ++t) {
    if (t < nsteps - 1) {
      A32_ISSUE_B((t << 6) + 64, (t & 1) ^ 1);
      A32_LOAD_A((t << 6) + 64);
    }
    __builtin_amdgcn_sched_barrier(0);
#pragma unroll
    for (int ks = 0; ks < 2; ++ks) {
      const int col = (lane >> 4) * 8 + ks * 32;
      bf16x8 af[4], bfr[4];
#pragma unroll
      for (int mt = 0; mt < 4; ++mt) {
        int row = wm + mt * 16 + (lane & 15);
        af[mt] = *(const bf16x8*)((const char*)&As[0] + row * 128 +
                                  ((col * 2) ^ ((row & 7) << 4)));
      }
#pragma unroll
      for (int nt = 0; nt < 4; ++nt) {
        int row = wn + nt * 16 + (lane & 15);
        bfr[nt] = *(const bf16x8*)((const char*)&Bs[t & 1][0] + row * 128 +
                                   ((col * 2) ^ ((row & 7) << 4)));
      }
#pragma unroll
      for (int mt = 0; mt < 4; ++mt)
#pragma unroll
        for (int nt = 0; nt < 4; ++nt)
          acc[mt][nt] = MFMA16(af[mt], bfr[nt], acc[mt][nt]);
    }
    __builtin_amdgcn_sched_barrier(0);
    if (t < nsteps - 1) {
      BAR();
      A32_CVT();
      asm volatile("s_waitcnt lgkmcnt(0)" ::: "memory");
      BAR();
    }
  }
#undef A32_ISSUE_B
#undef A32_LOAD_A
#undef A32_CVT

  float bv[4];
#pragma unroll
  for (int nt = 0; nt < 4; ++nt)
    bv[nt] = bias[n0 + wn + nt * 16 + (lane & 15)];
#pragma unroll
  for (int mt = 0; mt < 4; ++mt)
#pragma unroll
    for (int nt = 0; nt < 4; ++nt)
#pragma unroll
      for (int r = 0; r < 4; ++r) {
        int m = m0 + wm + mt * 16 + (lane >> 4) * 4 + r;
        int n = n0 + wn + nt * 16 + (lane & 15);
        Cout[(size_t)m * N + n] = f2bf(acc[mt][nt][r] + bv[nt]);
      }
}

// ---------------- GEMM (bf16 A), pipelined dbuf + T2 swizzle ----------------
template <bool OUT_BF16>
__global__ __launch_bounds__(256) void gemm_bf16(
    const u16* __restrict__ A, const u16* __restrict__ Bt,
    const float* __restrict__ bias, void* __restrict__ Cout,
    int M, int N, int K) {
  __shared__ __align__(16) u16 As[2][128 * 64];
  __shared__ __align__(16) u16 Bs[2][128 * 64];
  const int tid = threadIdx.x;
  const int lane = tid & 63;
  const int wave = tid >> 6;
  const int nwg = gridDim.x;
  const int id = blockIdx.x;
  const int sw = (id & 7) * (nwg >> 3) + (id >> 3);
  const int nx = N >> 7;
  const int m0 = (sw / nx) * 128;
  const int n0 = (sw % nx) * 128;
  const int wm = (wave >> 1) * 64;
  const int wn = (wave & 1) * 64;

  f32x4 acc[4][4] = {};

  const char* Abase = (const char*)A;
  const char* Bbase = (const char*)Bt;

#define STAGE_AB(ktile, buf)                                                   \
  _Pragma("unroll") for (int i = 0; i < 4; ++i) {                              \
    int flat = wave * 1024 + lane * 16 + i * 4096;                             \
    int row = flat >> 7;                                                       \
    int cb = flat & 127;                                                       \
    int scb = cb ^ ((row & 7) << 4);                                           \
    gload_lds16(Abase + ((size_t)(m0 + row) * K + (ktile)) * 2 + scb,          \
                (char*)&As[buf][0] + flat);                                    \
    gload_lds16(Bbase + ((size_t)(n0 + row) * K + (ktile)) * 2 + scb,          \
                (char*)&Bs[buf][0] + flat);                                    \
  }

  STAGE_AB(0, 0);

  const int nsteps = K >> 6;
  for (int t = 0; t < nsteps; ++t) {
    asm volatile("s_waitcnt vmcnt(0)" ::: "memory");
    BAR();
    if (t < nsteps - 1) STAGE_AB((t << 6) + 64, (t & 1) ^ 1);
#pragma unroll
    for (int ks = 0; ks < 2; ++ks) {
      const int col = (lane >> 4) * 8 + ks * 32;
      bf16x8 af[4], bfr[4];
#pragma unroll
      for (int mt = 0; mt < 4; ++mt) {
        int row = wm + mt * 16 + (lane & 15);
        af[mt] = *(const bf16x8*)((const char*)&As[t & 1][0] + row * 128 +
                                  ((col * 2) ^ ((row & 7) << 4)));
      }
#pragma unroll
      for (int nt = 0; nt < 4; ++nt) {
        int row = wn + nt * 16 + (lane & 15);
        bfr[nt] = *(const bf16x8*)((const char*)&Bs[t & 1][0] + row * 128 +
                                   ((col * 2) ^ ((row & 7) << 4)));
      }
#pragma unroll
      for (int mt = 0; mt < 4; ++mt)
#pragma unroll
        for (int nt = 0; nt < 4; ++nt)
          acc[mt][nt] = MFMA16(af[mt], bfr[nt], acc[mt][nt]);
    }
  }
#undef STAGE_AB

  float bv[4];
#pragma unroll
  for (int nt = 0; nt < 4; ++nt)
    bv[nt] = bias[n0 + wn + nt * 16 + (lane & 15)];
#pragma unroll
  for (int mt = 0; mt < 4; ++mt)
#pragma unroll
    for (int nt = 0; nt < 4; ++nt)
#pragma unroll
      for (int r = 0; r < 4; ++r) {
        int m = m0 + wm + mt * 16 + (lane >> 4) * 4 + r;
        int n = n0 + wn + nt * 16 + (lane & 15);
        float v = acc[mt][nt][r] + bv[nt];
        if (OUT_BF16)
          ((u16*)Cout)[(size_t)m * N + n] = f2bf(v);
        else
          ((float*)Cout)[(size_t)m * N + n] = v;
      }
}

// ---------------- flash attention (v14: compacted keys + idx PREFETCH) ----------
// Round-18 diagnosis: the idx gather created a serial chain idx-load -> (addr
// dep wait) -> gload_lds issue, exposing ~500-900cy per tile. Fix: preload the
// next tile's gather indices into registers one iteration early, so staging
// issues never wait on addresses. Everything else unchanged.
#define T_SEQ 2048
#define ROWQKV 3072
#define SCL 0.180336880f  /* (1/sqrt(64)) * log2(e) */

template <bool SPLIT>
__global__ __launch_bounds__(512) void attn_fwd(
    const u16* __restrict__ qkv, const int* __restrict__ idx,
    const int* __restrict__ cnt, u16* __restrict__ outp,
    float* __restrict__ Ml) {
  __shared__ __align__(16) u16 Ks[2][2][64 * 64];  // [buf][half][storerow][dk], swz s=row&7
  __shared__ __align__(16) u16 Vt[2][2][64 * 64];  // [buf][half][d][cpos], swz row^(row>>3)
  __shared__ __align__(16) u32 lut[256 * 4];       // byte -> 8 x bf16 {0,1}

  const int tid = threadIdx.x;
  const int lane = tid & 63;
  const int wave = tid >> 6;
  const int r15 = lane & 15;
  const int g = lane >> 4;
  const int id = blockIdx.x;
  const int hz = ((id >> 6) << 3) | (id & 7);
  const int qb = (id >> 3) & 7;
  const int h = SPLIT ? (hz >> 2) : (hz >> 1);
  const int z = SPLIT ? (hz & 3) : (hz & 1);
  const int split = SPLIT ? (z >> 1) : 0;
  const int b = SPLIT ? (z & 1) : z;
  const int q0 = qb * 256 + wave * 32;
  const size_t rowb = (size_t)b * T_SEQ;
  const int* idxb = idx + b * 2048;
  const int count = cnt[b];
  const int ntot = (count + 127) >> 7;
  const int nth = (ntot + 1) >> 1;
  const int t0 = (SPLIT && split) ? nth : 0;
  const int nt2 = SPLIT ? (split ? ntot - nth : nth) : ntot;

  // per-thread staging coordinates
  const int Lk = wave * 1024 + lane * 16;
  const int krow = Lk >> 7;
  const int kscb = (Lk & 127) ^ ((krow & 7) << 4);
  const int kprow = ((krow >> 4) & 1) * 32 + ((krow >> 2) & 3) * 8 +
                    (krow >> 5) * 4 + (krow & 3);
  const int vkey = tid >> 3;
  const int vd0 = (tid & 7) * 8;

  for (int i = tid; i < 256; i += 512) {
    union { u32 w[4]; bf16x8 v; } e;
#pragma unroll
    for (int j = 0; j < 4; ++j)
      e.w[j] = (((i >> (2 * j)) & 1) ? 0x3F80u : 0u) |
               (((i >> (2 * j + 1)) & 1) ? 0x3F800000u : 0u);
    *(bf16x8*)((char*)lut + i * 16) = e.v;
  }

  bf16x8 aq[2][2];
#pragma unroll
  for (int mt = 0; mt < 2; ++mt)
#pragma unroll
    for (int ks = 0; ks < 2; ++ks) {
      bf16x8 t = *(const bf16x8*)(qkv +
          (rowb + q0 + mt * 16 + r15) * ROWQKV + h * 64 + g * 8 + ks * 32);
#pragma unroll
      for (int j = 0; j < 8; ++j) t[j] = (short)f2bf(bf2f((u16)t[j]) * SCL);
      aq[mt][ks] = t;
    }

  f32x4 accO[2][4] = {};
  f32x4 ssum[2] = {};
  bf16x8 vr0, vr1;
  int ik0, ik1, iv0, iv1;  // prefetched gather indices for the NEXT tile

#define LOAD_IDX(ct)                                                           \
  {                                                                            \
    ik0 = idxb[(ct) * 128 + kprow];                                            \
    ik1 = idxb[(ct) * 128 + 64 + kprow];                                       \
    iv0 = idxb[(ct) * 128 + vkey];                                             \
    iv1 = idxb[(ct) * 128 + 64 + vkey];                                        \
  }

#define ISSUE_K2R(buf)                                                         \
  {                                                                            \
    gload_lds16((const char*)qkv +                                             \
                    ((rowb + ik0) * ROWQKV + 1024 + h * 64) * 2 + kscb,        \
                (char*)&Ks[buf][0][0] + wave * 1024);                          \
    gload_lds16((const char*)qkv +                                             \
                    ((rowb + ik1) * ROWQKV + 1024 + h * 64) * 2 + kscb,        \
                (char*)&Ks[buf][1][0] + wave * 1024);                          \
  }

#define LOAD_V2R()                                                             \
  {                                                                            \
    vr0 = *(const bf16x8*)(qkv + (rowb + iv0) * ROWQKV + 2048 + h * 64 + vd0); \
    vr1 = *(const bf16x8*)(qkv + (rowb + iv1) * ROWQKV + 2048 + h * 64 + vd0); \
  }

#define WRITE_V2(buf, ct)                                                      \
  {                                                                            \
    if ((ct) * 128 + vkey >= count) {                                          \
      bf16x8 zz = {};                                                          \
      vr0 = zz;                                                                \
    }                                                                          \
    if ((ct) * 128 + 64 + vkey >= count) {                                     \
      bf16x8 zz = {};                                                          \
      vr1 = zz;                                                                \
    }                                                                          \
    _Pragma("unroll") for (int j = 0; j < 8; ++j) {                            \
      int row = vd0 + j;                                                       \
      int sv = ((row ^ (row >> 3)) & 7) << 4;                                  \
      *(u16*)((char*)&Vt[buf][0][0] + row * 128 + ((vkey * 2) ^ sv)) =         \
          (u16)vr0[j];                                                         \
      *(u16*)((char*)&Vt[buf][1][0] + row * 128 + ((vkey * 2) ^ sv)) =         \
          (u16)vr1[j];                                                         \
    }                                                                          \
  }

#define COMPUTE_HALF(H, ct)                                                    \
  {                                                                            \
    f32x4 s[2][4] = {};                                                        \
    _Pragma("unroll") for (int ks = 0; ks < 2; ++ks) {                         \
      bf16x8 bk[4];                                                            \
      _Pragma("unroll") for (int nt = 0; nt < 4; ++nt) {                       \
        int row = nt * 16 + r15;                                               \
        int cb = (g * 8 + ks * 32) * 2;                                        \
        bk[nt] = *(const bf16x8*)((const char*)&Ks[cur][H][0] + row * 128 +    \
                                  (cb ^ ((row & 7) << 4)));                    \
      }                                                                        \
      _Pragma("unroll") for (int mt = 0; mt < 2; ++mt)                         \
        _Pragma("unroll") for (int nt = 0; nt < 4; ++nt)                       \
          s[mt][nt] = MFMA16(bk[nt], aq[mt][ks], s[mt][nt]);                   \
    }                                                                          \
    u32 pk[2][4][2];                                                           \
    _Pragma("unroll") for (int mt = 0; mt < 2; ++mt)                           \
      _Pragma("unroll") for (int nt = 0; nt < 4; ++nt) {                       \
        float e0 = exp2f(s[mt][nt][0]);                                        \
        float e1 = exp2f(s[mt][nt][1]);                                        \
        float e2 = exp2f(s[mt][nt][2]);                                        \
        float e3 = exp2f(s[mt][nt][3]);                                        \
        pk[mt][nt][0] = cvtpk_bf16(e0, e1);                                    \
        pk[mt][nt][1] = cvtpk_bf16(e2, e3);                                    \
      }                                                                        \
    __builtin_amdgcn_s_setprio(1);                                             \
    _Pragma("unroll") for (int ks = 0; ks < 2; ++ks) {                         \
      const int col = g * 8 + ks * 32;                                         \
      bf16x8 bv[4];                                                            \
      _Pragma("unroll") for (int nt = 0; nt < 4; ++nt) {                       \
        int row = nt * 16 + r15;                                               \
        int sv = ((row ^ (row >> 3)) & 7) << 4;                                \
        bv[nt] = *(const bf16x8*)((const char*)&Vt[cur][H][0] + row * 128 +    \
                                  ((col * 2) ^ sv));                           \
      }                                                                        \
      int rbase = count - ((ct) * 128 + (H) * 64 + ks * 32 + g * 8);           \
      int rr = rbase < 0 ? 0 : (rbase > 8 ? 8 : rbase);                        \
      u32 lb = (1u << rr) - 1u;                                                \
      bf16x8 mf = *(const bf16x8*)((const char*)lut + lb * 16);                \
      _Pragma("unroll") for (int mt = 0; mt < 2; ++mt) {                       \
        union { u32 w[4]; bf16x8 v; } ap;                                      \
        ap.w[0] = pk[mt][ks][0];                                               \
        ap.w[1] = pk[mt][ks][1];                                               \
        ap.w[2] = pk[mt][2 + ks][0];                                           \
        ap.w[3] = pk[mt][2 + ks][1];                                           \
        _Pragma("unroll") for (int nt = 0; nt < 4; ++nt)                       \
          accO[mt][nt] = MFMA16(ap.v, bv[nt], accO[mt][nt]);                   \
        ssum[mt] = MFMA16(ap.v, mf, ssum[mt]);                                 \
      }                                                                        \
    }                                                                          \
    __builtin_amdgcn_s_setprio(0);                                             \
  }

  if (nt2 > 0) {
    // prologue: idx(t0) -> staging(t0); prefetch idx(t0+1)
    LOAD_IDX(t0);
    ISSUE_K2R(0);
    LOAD_V2R();
    if (nt2 > 1) LOAD_IDX(t0 + 1);
    __syncthreads();  // drains staging + lut writes
    WRITE_V2(0, t0);
    asm volatile("s_waitcnt lgkmcnt(0)" ::: "memory");
    BAR();

    int cur = 0;
    for (int t = 0; t < nt2; ++t) {
      const int ct = t0 + t;
      if (t < nt2 - 1) {
        ISSUE_K2R(cur ^ 1);  // addresses already in regs (no wait)
        LOAD_V2R();
        if (t < nt2 - 2) LOAD_IDX(ct + 2);  // flies during compute
      }

      COMPUTE_HALF(0, ct);
      COMPUTE_HALF(1, ct);

      if (t < nt2 - 1) {
        asm volatile("s_waitcnt vmcnt(0)" ::: "memory");
        WRITE_V2(cur ^ 1, ct + 1);
        asm volatile("s_waitcnt lgkmcnt(0)" ::: "memory");
        BAR();
        cur ^= 1;
      }
    }
  }

  if (SPLIT) {
    u16* po = outp + (size_t)split * T_SEQ * 2 * 1024;
#pragma unroll
    for (int mt = 0; mt < 2; ++mt) {
#pragma unroll
      for (int r = 0; r < 4; ++r) {
        int q = q0 + mt * 16 + g * 4 + r;
#pragma unroll
        for (int nt = 0; nt < 4; ++nt)
          po[(rowb + q) * 1024 + h * 64 + nt * 16 + r15] = f2bf(accO[mt][nt][r]);
      }
      if (r15 == 0) {
        int idxm = ((split * 2 + b) * 16 + h) * T_SEQ + q0 + mt * 16 + g * 4;
        *(f32x4*)(Ml + idxm) = ssum[mt];
      }
    }
  } else {
#pragma unroll
    for (int mt = 0; mt < 2; ++mt)
#pragma unroll
      for (int r = 0; r < 4; ++r) {
        float inv = 1.f / ssum[mt][r];
        int q = q0 + mt * 16 + g * 4 + r;
#pragma unroll
        for (int nt = 0; nt < 4; ++nt)
          outp[(rowb + q) * 1024 + h * 64 + nt * 16 + r15] =
              f2bf(accO[mt][nt][r] * inv);
      }
  }
#undef LOAD_IDX
#undef ISSUE_K2R
#undef LOAD_V2R
#undef WRITE_V2
#undef COMPUTE_HALF
}

// ---------------- combine two KV-splits (m=0: just l0+l1) ----------------
__global__ __launch_bounds__(256) void attn_combine(
    const u16* __restrict__ part, const float* __restrict__ Ml,
    u16* __restrict__ att) {
  int idx = blockIdx.x * 256 + threadIdx.x;  // (B*T)*(H/8) = 524288
  int row = idx >> 7;                        // b*2048 + q
  int c8 = idx & 127;
  int col = c8 * 8;
  int h = c8 >> 3;
  int b = row >> 11, q = row & 2047;
  float l0 = Ml[(b * 16 + h) * T_SEQ + q];
  float l1 = Ml[((2 + b) * 16 + h) * T_SEQ + q];
  float inv = 1.f / (l0 + l1);
  bf16x8 o0 = *(const bf16x8*)(part + (size_t)row * 1024 + col);
  bf16x8 o1 = *(const bf16x8*)(part + (size_t)T_SEQ * 2 * 1024 +
                               (size_t)row * 1024 + col);
  bf16x8 o;
#pragma unroll
  for (int j = 0; j < 8; ++j)
    o[j] = (short)f2bf((bf2f((u16)o0[j]) + bf2f((u16)o1[j])) * inv);
  *(bf16x8*)(att + (size_t)row * 1024 + col) = o;
}

// ---------------- launch ----------------
extern "C" void kernel_launch(void* const* d_in, const int* in_sizes, int n_in,
                              void* d_out, int out_size, void* d_ws, size_t ws_size,
                              hipStream_t stream) {
  const float* x = (const float*)d_in[0];     // [2,2048,1024] f32
  const int* mask = (const int*)d_in[1];      // [2,1,1,2048] int32
  const float* Wqkv = (const float*)d_in[2];  // [1024,3072] f32
  const float* bqkv = (const float*)d_in[3];  // [3072] f32
  const float* Wout = (const float*)d_in[4];  // [1024,1024] f32
  const float* bout = (const float*)d_in[5];  // [1024] f32
  float* out = (float*)d_out;                 // [2,2048,1024] f32

  const int B = 2, T = 2048, H = 1024, M = B * T;

  u16* qkv = (u16*)d_ws;                       // M*3H
  u16* att = qkv + (size_t)M * 3 * H;          // M*H
  u16* WtQ = att + (size_t)M * H;              // 3H*H
  u16* WtO = WtQ + (size_t)3 * H * H;          // H*H
  u16* part = WtO + (size_t)H * H;             // 2 * M*H  (split partials)
  float* Ml = (float*)(part + (size_t)2 * M * H);  // 2*131072 floats
  int* idxb = (int*)(Ml + (size_t)2 * 131072);     // B*T ints
  int* cntb = idxb + B * T;                        // B ints

  const size_t need = ((size_t)M * 3 * H + (size_t)M * H + (size_t)3 * H * H +
                       (size_t)H * H + (size_t)2 * M * H) * 2 +
                      (size_t)2 * 131072 * 4 + (size_t)(B * T + 8) * 4;
  const bool split = ws_size >= need;

  transpose_weights<<<3072 + 1024, 256, 0, stream>>>(Wqkv, WtQ, Wout, WtO);
  mask_compact<<<B, 512, 0, stream>>>(mask, idxb, cntb);
  gemm_a32_bf16<<<(3 * H / 128) * (M / 128), 256, 0, stream>>>(x, WtQ, bqkv, qkv, M, 3 * H, H);
  if (split) {
    attn_fwd<true><<<512, 512, 0, stream>>>(qkv, idxb, cntb, part, Ml);
    attn_combine<<<(M * H / 8 + 255) / 256, 256, 0, stream>>>(part, Ml, att);
  } else {
    attn_fwd<false><<<256, 512, 0, stream>>>(qkv, idxb, cntb, att, Ml);
  }
  gemm_bf16<false><<<(H / 128) * (M / 128), 256, 0, stream>>>(att, WtO, bout, out, M, H, H);
}